// Round 7
// baseline (317.716 us; speedup 1.0000x reference)
//
#include <hip/hip_runtime.h>
#include <hip/hip_bf16.h>

// Problem constants
#define NB 16
#define NN 800
#define NCACHE 128
#define NL 928      // NN + NCACHE
#define CC 1024
#define NH 16
#define HD 64

typedef __attribute__((ext_vector_type(8))) short bf16x8;
typedef __attribute__((ext_vector_type(4))) float f32x4;
typedef __attribute__((ext_vector_type(2))) __bf16 bf2;

__device__ __forceinline__ short f2bf(float x) {
  union { float f; unsigned u; } c; c.f = x;
  unsigned r = c.u + 0x7fffu + ((c.u >> 16) & 1u);
  return (short)(r >> 16);
}

#define GLD_LDS(gp, lp) __builtin_amdgcn_global_load_lds( \
    (__attribute__((address_space(1))) void*)(gp),        \
    (__attribute__((address_space(3))) void*)(lp), 16, 0, 0)

#define BAR() asm volatile("s_barrier" ::: "memory")

// ---------------------------------------------------------------------------
// prep_kv: k_in = bf16(concat(x+xpos, k_t)); v_in = bf16(concat(x, v_t))
// ---------------------------------------------------------------------------
__global__ __launch_bounds__(256) void prep_kv(
    const float* __restrict__ x, const float* __restrict__ xpos,
    const float* __restrict__ ktc, const float* __restrict__ vtc,
    short* __restrict__ k_in, short* __restrict__ v_in) {
  int idx = blockIdx.x * 256 + threadIdx.x;   // 0 .. 16*928*128-1
  int chunk = idx & 127;
  int row = idx >> 7;                          // 0..14847
  int b = row / NL;
  int lr = row - b * NL;
  int c = chunk * 8;
  float vk[8], vv[8];
  if (lr < NN) {
    const float4* px = (const float4*)(x + ((size_t)(b * NN + lr) * CC + c));
    const float4* pp = (const float4*)(xpos + ((size_t)(b * NN + lr) * CC + c));
    float4 x0 = px[0], x1 = px[1], p0 = pp[0], p1 = pp[1];
    vv[0]=x0.x; vv[1]=x0.y; vv[2]=x0.z; vv[3]=x0.w;
    vv[4]=x1.x; vv[5]=x1.y; vv[6]=x1.z; vv[7]=x1.w;
    vk[0]=x0.x+p0.x; vk[1]=x0.y+p0.y; vk[2]=x0.z+p0.z; vk[3]=x0.w+p0.w;
    vk[4]=x1.x+p1.x; vk[5]=x1.y+p1.y; vk[6]=x1.z+p1.z; vk[7]=x1.w+p1.w;
  } else {
    const float4* pk = (const float4*)(ktc + ((size_t)(b * NCACHE + lr - NN) * CC + c));
    const float4* pv = (const float4*)(vtc + ((size_t)(b * NCACHE + lr - NN) * CC + c));
    float4 k0 = pk[0], k1 = pk[1], v0 = pv[0], v1 = pv[1];
    vk[0]=k0.x; vk[1]=k0.y; vk[2]=k0.z; vk[3]=k0.w;
    vk[4]=k1.x; vk[5]=k1.y; vk[6]=k1.z; vk[7]=k1.w;
    vv[0]=v0.x; vv[1]=v0.y; vv[2]=v0.z; vv[3]=v0.w;
    vv[4]=v1.x; vv[5]=v1.y; vv[6]=v1.z; vv[7]=v1.w;
  }
  bf16x8 ok, ov;
#pragma unroll
  for (int i = 0; i < 8; ++i) { ok[i] = f2bf(vk[i]); ov[i] = f2bf(vv[i]); }
  *(bf16x8*)(k_in + (size_t)row * CC + c) = ok;
  *(bf16x8*)(v_in + (size_t)row * CC + c) = ov;
}

// ---------------------------------------------------------------------------
// prep_w: 4 weights -> bf16 contiguous; Wq scaled by HD^-0.5 * log2(e).
// ---------------------------------------------------------------------------
__global__ __launch_bounds__(256) void prep_w(
    const float* __restrict__ Wq, const float* __restrict__ Wk,
    const float* __restrict__ Wv, const float* __restrict__ Wp,
    short* __restrict__ wout) {
  int idx = blockIdx.x * 256 + threadIdx.x;  // 0..524287
  int wsel = idx >> 17;
  int off = (idx & 131071) * 8;
  const float* src = wsel == 0 ? Wq : wsel == 1 ? Wk : wsel == 2 ? Wv : Wp;
  float sc = wsel == 0 ? 0.18033688011112042f : 1.0f;  // 0.125 * log2(e)
  const float4* p = (const float4*)(src + off);
  float4 a = p[0], b = p[1];
  bf16x8 o;
  o[0]=f2bf(a.x*sc); o[1]=f2bf(a.y*sc); o[2]=f2bf(a.z*sc); o[3]=f2bf(a.w*sc);
  o[4]=f2bf(b.x*sc); o[5]=f2bf(b.y*sc); o[6]=f2bf(b.z*sc); o[7]=f2bf(b.w*sc);
  *(bf16x8*)(wout + (size_t)wsel * 1048576 + off) = o;
}

// ---------------------------------------------------------------------------
// gemm256 v3: 256x256 tile, BK=64. A staged in LDS (64 KiB double-buffered,
// XOR-chunk swizzle, gload_lds). B (weights, L2-resident) STREAMED from
// global into registers each K-tile -- removes 96 KB/K-tile of LDS traffic
// (B reads 64 KB + writes 32 KB), putting MFMA back on the critical path.
// Per K-tile: [issue 8 B global loads] [stage A(t+1): 4 gload_lds]
// [vmcnt(12) = A(t) landed; B(t)+A(t+1) in flight] [BAR] [16 A ds_reads +
// 64 MFMA; compiler inserts vmcnt for B-reg deps under the ds_read drain]
// [BAR]. XCD swizzle is bm-fastest: each XCD pins ONE 512KB B panel in L2.
// MODE 1: f32 out + bias (proj). MODE 2: qk fused N=2048. MODE 3: v + fused
// transpose into vt[(b*16+h)*64+d][928].
// ---------------------------------------------------------------------------
#define READ_A8(dst, QR) \
  _Pragma("unroll") \
  for (int fr = 0; fr < 4; ++fr) \
    _Pragma("unroll") \
    for (int ks = 0; ks < 2; ++ks) \
      dst[fr][ks] = *(const bf16x8*)&lds[abase + (QR)*4096 + fr*1024 + (ks ? xk1 : xk0)];

#define MFMA_HALF(QR, asrc) \
  _Pragma("unroll") \
  for (int fr = 0; fr < 4; ++fr) \
    _Pragma("unroll") \
    for (int fc = 0; fc < 4; ++fc) \
      _Pragma("unroll") \
      for (int ks = 0; ks < 2; ++ks) \
        acc[(QR)*4+fr][fc] = __builtin_amdgcn_mfma_f32_16x16x32_bf16( \
            asrc[fr][ks], bfv[fc][ks], acc[(QR)*4+fr][fc], 0, 0, 0);

template<int MODE>
__global__ __launch_bounds__(512, 2) void gemm256(
    const short* __restrict__ A, const short* __restrict__ Bw,
    short* __restrict__ o0, short* __restrict__ o1,
    float* __restrict__ of, const float* __restrict__ bias) {
  __shared__ short lds[32768];   // 64 KiB: parity p at p*16384 shorts (A only)
  const int tid = threadIdx.x;
  const int w = tid >> 6, l = tid & 63;
  const int wm = w >> 2, wn = w & 3;
  const int c = l & 15, g2 = l >> 4;
  const int BNT = (MODE == 2) ? 8 : 4;
  const int nBM = gridDim.x / BNT;
  const int cpx = gridDim.x >> 3;
  const int swz = (blockIdx.x & 7) * cpx + (blockIdx.x >> 3);
  const int bn = swz / nBM, bm = swz % nBM;   // bm-fastest: 1 B panel per XCD
  const int m0 = bm * 256, n0 = bn * 256;

  // A staging source (per-lane, chunk-XOR pre-swizzled)
  const int R0 = tid >> 3;                   // 0..63
  const int gc0 = (tid & 7) ^ (R0 & 7);
  const short* As_ = A + (size_t)(m0 + R0) * CC + gc0 * 8;
  const int wofs = w * 512;                  // wave-uniform lds chunk base

#define STAGE_HT(slot, src) do { \
    GLD_LDS((src), &lds[(slot) + wofs]); \
    GLD_LDS((src) + 64 * CC, &lds[(slot) + 4096 + wofs]); } while (0)

  // B streaming source: lane reads W row (n0 + wn*64 + fc*16 + c), k g2*8
  const short* Bp = Bw + (size_t)(n0 + wn * 64 + c) * CC + g2 * 8;

  // ds_read swizzled k-chunk offsets (shorts)
  const int xk0 = ((g2) ^ (c & 7)) * 8;
  const int xk1 = ((g2 + 4) ^ (c & 7)) * 8;

  f32x4 acc[8][4] = {};

  // prologue: stage A tile 0 into parity 0
  STAGE_HT(0,    As_);
  STAGE_HT(8192, As_ + 128 * CC);

#pragma unroll 1
  for (int t = 0; t < 16; ++t) {
    const int pb = (t & 1) << 14;        // parity holding A tile t
    const int pn = pb ^ 16384;           // parity for tile t+1
    // issue B(t) global loads (retire under the A ds_read drain after BAR)
    bf16x8 bfv[4][2];
    const short* Bpt = Bp + t * 64;
#pragma unroll
    for (int fc = 0; fc < 4; ++fc)
#pragma unroll
      for (int ks = 0; ks < 2; ++ks)
        bfv[fc][ks] = *(const bf16x8*)(Bpt + fc * 16 * CC + ks * 32);
    if (t < 15) {
      const short* as1 = As_ + (t + 1) * 64;
      STAGE_HT(pn,        as1);
      STAGE_HT(pn + 8192, as1 + 128 * CC);
      // outstanding: A(t):4 oldest + B(t):8 + A(t+1):4 -> wait retires A(t)
      asm volatile("s_waitcnt vmcnt(12)" ::: "memory");
    } else {
      // outstanding: A(15):4 oldest + B(15):8
      asm volatile("s_waitcnt vmcnt(8)" ::: "memory");
    }
    BAR();   // cross-wave: A tile t fully visible
    const int abase = pb + wm * 8192 + c * 64;
    bf16x8 afA[4][2], afB[4][2];
    READ_A8(afA, 0);
    __builtin_amdgcn_s_setprio(1);
    MFMA_HALF(0, afA);
    __builtin_amdgcn_s_setprio(0);
    READ_A8(afB, 1);
    __builtin_amdgcn_s_setprio(1);
    MFMA_HALF(1, afB);
    __builtin_amdgcn_s_setprio(0);
    BAR();   // all waves consumed parity pb -> next iter may stage into it
  }

  // epilogue
#pragma unroll
  for (int fr = 0; fr < 8; ++fr)
#pragma unroll
    for (int fc = 0; fc < 4; ++fc) {
      const int row = m0 + wm * 128 + fr * 16 + g2 * 4;
      const int colw = wn * 64 + fc * 16 + c;
      if (MODE == 1) {
        const int col = n0 + colw;
        const float bv = bias[col];
#pragma unroll
        for (int j = 0; j < 4; ++j)
          of[(size_t)(row + j) * CC + col] = acc[fr][fc][j] + bv;
      } else if (MODE == 2) {
        const int col2 = n0 + colw;
        short* base = (col2 < 1024) ? o0 : o1;
        const int col = col2 & 1023;
#pragma unroll
        for (int j = 0; j < 4; ++j)
          base[(size_t)(row + j) * CC + col] = f2bf(acc[fr][fc][j]);
      } else {  // MODE 3: transposed store into vt[(b*16+h)*64+d][NL]
        const int col = n0 + colw;
        const int b = row / NL;
        const int rb = row - b * NL;      // rows row..row+3 never straddle 928
        const int vtrow = (b * NH + (col >> 6)) * HD + (col & 63);
        ushort4 pk4;
        pk4.x = (unsigned short)f2bf(acc[fr][fc][0]);
        pk4.y = (unsigned short)f2bf(acc[fr][fc][1]);
        pk4.z = (unsigned short)f2bf(acc[fr][fc][2]);
        pk4.w = (unsigned short)f2bf(acc[fr][fc][3]);
        *(ushort4*)(o0 + (size_t)vtrow * NL + rb) = pk4;
      }
    }
}

// ---------------------------------------------------------------------------
// attn_fwd v4: flash attention, no-max softmax, block-shared LDS K/V tiles.
// (unchanged)
// ---------------------------------------------------------------------------
__global__ __launch_bounds__(256, 4) void attn_fwd(
    const short* __restrict__ qb, const short* __restrict__ kbuf,
    const short* __restrict__ vtb, short* __restrict__ ob) {
  __shared__ short smem[2][4096];   // per buf: K [32][64] @0, V^T [64][32] @2048
  const int tid = threadIdx.x;
  const int w = tid >> 6;           // wave 0..3
  const int l = tid & 63;
  const int c = l & 15, g = l >> 4;
  const int swzb = (blockIdx.x & 7) * 224 + (blockIdx.x >> 3);
  const int bh = swzb / 7;
  const int blk7 = swzb - bh * 7;
  const int h = bh & 15, b = bh >> 4;
  const int q0 = blk7 * 128 + w * 32;
  const bool active = q0 < NN;

  const int u = l >> 3;                    // 0..7
  const int lK = 8 * w + u;                // LDS K row
  const int b16 = lK & 15;
  const int rpK = 8 * (b16 >> 2) + (b16 & 3) + 4 * (lK >> 4);
  const int xK = (l & 7) ^ u;
  const short* srcK = kbuf + (size_t)b * NL * CC + (size_t)rpK * CC + h * HD + xK * 8;
  const int dV = 16 * w + (l >> 2);
  const int xV = (l & 3) ^ ((l >> 3) & 3);
  const short* srcV = vtb + (size_t)bh * HD * NL + (size_t)dV * NL + xV * 8;

  bf16x8 qf[2][2];
  if (active) {
#pragma unroll
    for (int f = 0; f < 2; ++f) {
      const short* qrow = qb + ((size_t)(b * NL + q0 + f * 16 + c) * CC + h * HD + g * 8);
      qf[f][0] = *(const bf16x8*)qrow;
      qf[f][1] = *(const bf16x8*)(qrow + 32);
    }
  }

  const int koff0 = c * 64 + ((g ^ (c & 7)) << 3);
  const int koff1 = c * 64 + (((g + 4) ^ (c & 7)) << 3);
  const int voffb = 2048 + c * 32 + ((g ^ ((c >> 1) & 3)) << 3);

  f32x4 acc[2][4] = {};
  f32x4 ellv[2] = {};

  GLD_LDS(srcK, &smem[0][w * 512]);
  GLD_LDS(srcV, &smem[0][2048 + w * 512]);
  __syncthreads();

  int buf = 0;
  for (int t = 0; t < 29; ++t) {
    if (t < 28) {
      GLD_LDS(srcK + (size_t)(t + 1) * 32 * CC, &smem[buf ^ 1][w * 512]);
      GLD_LDS(srcV + (t + 1) * 32, &smem[buf ^ 1][2048 + w * 512]);
    }
    if (active) {
      const short* S = smem[buf];
      bf16x8 kd0 = *(const bf16x8*)(S + koff0);
      bf16x8 kd1 = *(const bf16x8*)(S + koff1);
      bf16x8 kd2 = *(const bf16x8*)(S + koff0 + 1024);
      bf16x8 kd3 = *(const bf16x8*)(S + koff1 + 1024);
      bf16x8 vf0 = *(const bf16x8*)(S + voffb);
      bf16x8 vf1 = *(const bf16x8*)(S + voffb + 512);
      bf16x8 vf2 = *(const bf16x8*)(S + voffb + 1024);
      bf16x8 vf3 = *(const bf16x8*)(S + voffb + 1536);
      __builtin_amdgcn_s_setprio(1);
#pragma unroll
      for (int f = 0; f < 2; ++f) {
        f32x4 z = {0.f, 0.f, 0.f, 0.f};
        f32x4 s0 = __builtin_amdgcn_mfma_f32_16x16x32_bf16(kd0, qf[f][0], z, 0, 0, 0);
        s0 = __builtin_amdgcn_mfma_f32_16x16x32_bf16(kd1, qf[f][1], s0, 0, 0, 0);
        f32x4 s1 = __builtin_amdgcn_mfma_f32_16x16x32_bf16(kd2, qf[f][0], z, 0, 0, 0);
        s1 = __builtin_amdgcn_mfma_f32_16x16x32_bf16(kd3, qf[f][1], s1, 0, 0, 0);
        f32x4 e0, e1;
        e0[0] = __builtin_amdgcn_exp2f(s0[0]);
        e0[1] = __builtin_amdgcn_exp2f(s0[1]);
        e0[2] = __builtin_amdgcn_exp2f(s0[2]);
        e0[3] = __builtin_amdgcn_exp2f(s0[3]);
        e1[0] = __builtin_amdgcn_exp2f(s1[0]);
        e1[1] = __builtin_amdgcn_exp2f(s1[1]);
        e1[2] = __builtin_amdgcn_exp2f(s1[2]);
        e1[3] = __builtin_amdgcn_exp2f(s1[3]);
        ellv[f] += e0 + e1;
        union { bf2 h2[4]; bf16x8 v; } pu;
        pu.h2[0] = bf2{(__bf16)e0[0], (__bf16)e0[1]};
        pu.h2[1] = bf2{(__bf16)e0[2], (__bf16)e0[3]};
        pu.h2[2] = bf2{(__bf16)e1[0], (__bf16)e1[1]};
        pu.h2[3] = bf2{(__bf16)e1[2], (__bf16)e1[3]};
        acc[f][0] = __builtin_amdgcn_mfma_f32_16x16x32_bf16(pu.v, vf0, acc[f][0], 0, 0, 0);
        acc[f][1] = __builtin_amdgcn_mfma_f32_16x16x32_bf16(pu.v, vf1, acc[f][1], 0, 0, 0);
        acc[f][2] = __builtin_amdgcn_mfma_f32_16x16x32_bf16(pu.v, vf2, acc[f][2], 0, 0, 0);
        acc[f][3] = __builtin_amdgcn_mfma_f32_16x16x32_bf16(pu.v, vf3, acc[f][3], 0, 0, 0);
      }
      __builtin_amdgcn_s_setprio(0);
    }
    __syncthreads();
    buf ^= 1;
  }

  if (active) {
    float rinv[2];
#pragma unroll
    for (int f = 0; f < 2; ++f) {
      float e = (ellv[f][0] + ellv[f][1]) + (ellv[f][2] + ellv[f][3]);
      e += __shfl_xor(e, 16);
      e += __shfl_xor(e, 32);
      rinv[f] = 1.0f / e;
    }
#pragma unroll
    for (int f = 0; f < 2; ++f) {
      float rj[4];
#pragma unroll
      for (int j = 0; j < 4; ++j) rj[j] = __shfl(rinv[f], g * 4 + j);
      short* orow = ob + (size_t)(b * NN + q0 + f * 16 + g * 4) * CC + h * HD + c;
#pragma unroll
      for (int n = 0; n < 4; ++n)
#pragma unroll
        for (int j = 0; j < 4; ++j)
          orow[(size_t)j * CC + n * 16] = f2bf(acc[f][n][j] * rj[j]);
    }
  }
}

// ---------------------------------------------------------------------------
extern "C" void kernel_launch(void* const* d_in, const int* in_sizes, int n_in,
                              void* d_out, int out_size, void* d_ws, size_t ws_size,
                              hipStream_t stream) {
  const float* x    = (const float*)d_in[0];
  const float* xpos = (const float*)d_in[1];
  const float* k_t  = (const float*)d_in[2];
  const float* v_t  = (const float*)d_in[3];
  const float* Wq   = (const float*)d_in[4];
  const float* Wk   = (const float*)d_in[5];
  const float* Wv   = (const float*)d_in[6];
  const float* Wp   = (const float*)d_in[7];
  const float* bp   = (const float*)d_in[8];
  float* out = (float*)d_out;

  // workspace layout (bytes), total 160,432,128
  char* ws = (char*)d_ws;
  short* k_in = (short*)ws;                       // 30,408,704  [16*928,1024] bf16
  short* v_in = (short*)(ws + 30408704);          // 30,408,704
  short* wqb  = (short*)(ws + 60817408);          // 4 x 2,097,152 (Wq|Wk|Wv|Wp)
  short* wvb  = (short*)(ws + 65011712);
  short* wpb  = (short*)(ws + 67108864);
  short* qbuf = (short*)(ws + 69206016);          // 30,408,704
  short* kbuf = (short*)(ws + 99614720);          // 30,408,704
  short* vtb  = (short*)(ws + 130023424);         // 30,408,704  vt[(b*16+h)*64+d][928]
  short* attn_o = k_in;   // alias: k_in dead after fused qk GEMM

  prep_kv<<<7424, 256, 0, stream>>>(x, xpos, k_t, v_t, k_in, v_in);
  prep_w<<<2048, 256, 0, stream>>>(Wq, Wk, Wv, Wp, wqb);
  // fused q|k projection: Bw = [Wq_scaled ; Wk] (2048 rows, contiguous in ws)
  gemm256<2><<<464, 512, 0, stream>>>(k_in, wqb, qbuf, kbuf, nullptr, nullptr);
  // v projection with fused transpose into vt
  gemm256<3><<<232, 512, 0, stream>>>(v_in, wvb, vtb, nullptr, nullptr, nullptr);
  attn_fwd<<<1792, 256, 0, stream>>>(qbuf, kbuf, vtb, attn_o);
  gemm256<1><<<200, 512, 0, stream>>>(attn_o, wpb, nullptr, nullptr, out, bp);
}

// Round 8
// 317.056 us; speedup vs baseline: 1.0021x; 1.0021x over previous
//
#include <hip/hip_runtime.h>
#include <hip/hip_bf16.h>

// Problem constants
#define NB 16
#define NN 800
#define NCACHE 128
#define NL 928      // NN + NCACHE
#define CC 1024
#define NH 16
#define HD 64

typedef __attribute__((ext_vector_type(8))) short bf16x8;
typedef __attribute__((ext_vector_type(4))) float f32x4;
typedef __attribute__((ext_vector_type(2))) __bf16 bf2;

__device__ __forceinline__ short f2bf(float x) {
  union { float f; unsigned u; } c; c.f = x;
  unsigned r = c.u + 0x7fffu + ((c.u >> 16) & 1u);
  return (short)(r >> 16);
}

#define GLD_LDS(gp, lp) __builtin_amdgcn_global_load_lds( \
    (__attribute__((address_space(1))) void*)(gp),        \
    (__attribute__((address_space(3))) void*)(lp), 16, 0, 0)

#define BAR() asm volatile("s_barrier" ::: "memory")

// ---------------------------------------------------------------------------
// prep_kv: k_in = bf16(concat(x+xpos, k_t)); v_in = bf16(concat(x, v_t))
// ---------------------------------------------------------------------------
__global__ __launch_bounds__(256) void prep_kv(
    const float* __restrict__ x, const float* __restrict__ xpos,
    const float* __restrict__ ktc, const float* __restrict__ vtc,
    short* __restrict__ k_in, short* __restrict__ v_in) {
  int idx = blockIdx.x * 256 + threadIdx.x;   // 0 .. 16*928*128-1
  int chunk = idx & 127;
  int row = idx >> 7;                          // 0..14847
  int b = row / NL;
  int lr = row - b * NL;
  int c = chunk * 8;
  float vk[8], vv[8];
  if (lr < NN) {
    const float4* px = (const float4*)(x + ((size_t)(b * NN + lr) * CC + c));
    const float4* pp = (const float4*)(xpos + ((size_t)(b * NN + lr) * CC + c));
    float4 x0 = px[0], x1 = px[1], p0 = pp[0], p1 = pp[1];
    vv[0]=x0.x; vv[1]=x0.y; vv[2]=x0.z; vv[3]=x0.w;
    vv[4]=x1.x; vv[5]=x1.y; vv[6]=x1.z; vv[7]=x1.w;
    vk[0]=x0.x+p0.x; vk[1]=x0.y+p0.y; vk[2]=x0.z+p0.z; vk[3]=x0.w+p0.w;
    vk[4]=x1.x+p1.x; vk[5]=x1.y+p1.y; vk[6]=x1.z+p1.z; vk[7]=x1.w+p1.w;
  } else {
    const float4* pk = (const float4*)(ktc + ((size_t)(b * NCACHE + lr - NN) * CC + c));
    const float4* pv = (const float4*)(vtc + ((size_t)(b * NCACHE + lr - NN) * CC + c));
    float4 k0 = pk[0], k1 = pk[1], v0 = pv[0], v1 = pv[1];
    vk[0]=k0.x; vk[1]=k0.y; vk[2]=k0.z; vk[3]=k0.w;
    vk[4]=k1.x; vk[5]=k1.y; vk[6]=k1.z; vk[7]=k1.w;
    vv[0]=v0.x; vv[1]=v0.y; vv[2]=v0.z; vv[3]=v0.w;
    vv[4]=v1.x; vv[5]=v1.y; vv[6]=v1.z; vv[7]=v1.w;
  }
  bf16x8 ok, ov;
#pragma unroll
  for (int i = 0; i < 8; ++i) { ok[i] = f2bf(vk[i]); ov[i] = f2bf(vv[i]); }
  *(bf16x8*)(k_in + (size_t)row * CC + c) = ok;
  *(bf16x8*)(v_in + (size_t)row * CC + c) = ov;
}

// ---------------------------------------------------------------------------
// prep_w: 4 weights -> bf16 contiguous; Wq scaled by HD^-0.5 * log2(e).
// ---------------------------------------------------------------------------
__global__ __launch_bounds__(256) void prep_w(
    const float* __restrict__ Wq, const float* __restrict__ Wk,
    const float* __restrict__ Wv, const float* __restrict__ Wp,
    short* __restrict__ wout) {
  int idx = blockIdx.x * 256 + threadIdx.x;  // 0..524287
  int wsel = idx >> 17;
  int off = (idx & 131071) * 8;
  const float* src = wsel == 0 ? Wq : wsel == 1 ? Wk : wsel == 2 ? Wv : Wp;
  float sc = wsel == 0 ? 0.18033688011112042f : 1.0f;  // 0.125 * log2(e)
  const float4* p = (const float4*)(src + off);
  float4 a = p[0], b = p[1];
  bf16x8 o;
  o[0]=f2bf(a.x*sc); o[1]=f2bf(a.y*sc); o[2]=f2bf(a.z*sc); o[3]=f2bf(a.w*sc);
  o[4]=f2bf(b.x*sc); o[5]=f2bf(b.y*sc); o[6]=f2bf(b.z*sc); o[7]=f2bf(b.w*sc);
  *(bf16x8*)(wout + (size_t)wsel * 1048576 + off) = o;
}

// ---------------------------------------------------------------------------
// gemm256 v3: 256x256 tile, BK=64. A staged in LDS (64 KiB double-buffered,
// XOR-chunk swizzle, gload_lds). B (weights, L2-resident) STREAMED from
// global into registers each K-tile -- removes 96 KB/K-tile of LDS traffic
// (B reads 64 KB + writes 32 KB), putting MFMA back on the critical path.
// Per K-tile: [issue 8 B global loads] [stage A(t+1): 4 gload_lds]
// [vmcnt(12) = A(t) landed; B(t)+A(t+1) in flight] [BAR] [16 A ds_reads +
// 64 MFMA; compiler inserts vmcnt for B-reg deps under the ds_read drain]
// [BAR]. XCD swizzle is bm-fastest: each XCD pins ONE 512KB B panel in L2.
// MODE 1: f32 out + bias (proj). MODE 2: qk fused N=2048. MODE 3: v + fused
// transpose into vt[(b*16+h)*64+d][928].
// ---------------------------------------------------------------------------
#define READ_A8(dst, QR) \
  _Pragma("unroll") \
  for (int fr = 0; fr < 4; ++fr) \
    _Pragma("unroll") \
    for (int ks = 0; ks < 2; ++ks) \
      dst[fr][ks] = *(const bf16x8*)&lds[abase + (QR)*4096 + fr*1024 + (ks ? xk1 : xk0)];

#define MFMA_HALF(QR, asrc) \
  _Pragma("unroll") \
  for (int fr = 0; fr < 4; ++fr) \
    _Pragma("unroll") \
    for (int fc = 0; fc < 4; ++fc) \
      _Pragma("unroll") \
      for (int ks = 0; ks < 2; ++ks) \
        acc[(QR)*4+fr][fc] = __builtin_amdgcn_mfma_f32_16x16x32_bf16( \
            asrc[fr][ks], bfv[fc][ks], acc[(QR)*4+fr][fc], 0, 0, 0);

template<int MODE>
__global__ __launch_bounds__(512, 2) void gemm256(
    const short* __restrict__ A, const short* __restrict__ Bw,
    short* __restrict__ o0, short* __restrict__ o1,
    float* __restrict__ of, const float* __restrict__ bias) {
  __shared__ short lds[32768];   // 64 KiB: parity p at p*16384 shorts (A only)
  const int tid = threadIdx.x;
  const int w = tid >> 6, l = tid & 63;
  const int wm = w >> 2, wn = w & 3;
  const int c = l & 15, g2 = l >> 4;
  const int BNT = (MODE == 2) ? 8 : 4;
  const int nBM = gridDim.x / BNT;
  const int cpx = gridDim.x >> 3;
  const int swz = (blockIdx.x & 7) * cpx + (blockIdx.x >> 3);
  const int bn = swz / nBM, bm = swz % nBM;   // bm-fastest: 1 B panel per XCD
  const int m0 = bm * 256, n0 = bn * 256;

  // A staging source (per-lane, chunk-XOR pre-swizzled)
  const int R0 = tid >> 3;                   // 0..63
  const int gc0 = (tid & 7) ^ (R0 & 7);
  const short* As_ = A + (size_t)(m0 + R0) * CC + gc0 * 8;
  const int wofs = w * 512;                  // wave-uniform lds chunk base

#define STAGE_HT(slot, src) do { \
    GLD_LDS((src), &lds[(slot) + wofs]); \
    GLD_LDS((src) + 64 * CC, &lds[(slot) + 4096 + wofs]); } while (0)

  // B streaming source: lane reads W row (n0 + wn*64 + fc*16 + c), k g2*8
  const short* Bp = Bw + (size_t)(n0 + wn * 64 + c) * CC + g2 * 8;

  // ds_read swizzled k-chunk offsets (shorts)
  const int xk0 = ((g2) ^ (c & 7)) * 8;
  const int xk1 = ((g2 + 4) ^ (c & 7)) * 8;

  f32x4 acc[8][4] = {};

  // prologue: stage A tile 0 into parity 0
  STAGE_HT(0,    As_);
  STAGE_HT(8192, As_ + 128 * CC);

#pragma unroll 1
  for (int t = 0; t < 16; ++t) {
    const int pb = (t & 1) << 14;        // parity holding A tile t
    const int pn = pb ^ 16384;           // parity for tile t+1
    // issue B(t) global loads (retire under the A ds_read drain after BAR)
    bf16x8 bfv[4][2];
    const short* Bpt = Bp + t * 64;
#pragma unroll
    for (int fc = 0; fc < 4; ++fc)
#pragma unroll
      for (int ks = 0; ks < 2; ++ks)
        bfv[fc][ks] = *(const bf16x8*)(Bpt + fc * 16 * CC + ks * 32);
    if (t < 15) {
      const short* as1 = As_ + (t + 1) * 64;
      STAGE_HT(pn,        as1);
      STAGE_HT(pn + 8192, as1 + 128 * CC);
      // outstanding: A(t):4 oldest + B(t):8 + A(t+1):4 -> wait retires A(t)
      asm volatile("s_waitcnt vmcnt(12)" ::: "memory");
    } else {
      // outstanding: A(15):4 oldest + B(15):8
      asm volatile("s_waitcnt vmcnt(8)" ::: "memory");
    }
    BAR();   // cross-wave: A tile t fully visible
    const int abase = pb + wm * 8192 + c * 64;
    bf16x8 afA[4][2], afB[4][2];
    READ_A8(afA, 0);
    __builtin_amdgcn_s_setprio(1);
    MFMA_HALF(0, afA);
    __builtin_amdgcn_s_setprio(0);
    READ_A8(afB, 1);
    __builtin_amdgcn_s_setprio(1);
    MFMA_HALF(1, afB);
    __builtin_amdgcn_s_setprio(0);
    BAR();   // all waves consumed parity pb -> next iter may stage into it
  }

  // epilogue
#pragma unroll
  for (int fr = 0; fr < 8; ++fr)
#pragma unroll
    for (int fc = 0; fc < 4; ++fc) {
      const int row = m0 + wm * 128 + fr * 16 + g2 * 4;
      const int colw = wn * 64 + fc * 16 + c;
      if (MODE == 1) {
        const int col = n0 + colw;
        const float bv = bias[col];
#pragma unroll
        for (int j = 0; j < 4; ++j)
          of[(size_t)(row + j) * CC + col] = acc[fr][fc][j] + bv;
      } else if (MODE == 2) {
        const int col2 = n0 + colw;
        short* base = (col2 < 1024) ? o0 : o1;
        const int col = col2 & 1023;
#pragma unroll
        for (int j = 0; j < 4; ++j)
          base[(size_t)(row + j) * CC + col] = f2bf(acc[fr][fc][j]);
      } else {  // MODE 3: transposed store into vt[(b*16+h)*64+d][NL]
        const int col = n0 + colw;
        const int b = row / NL;
        const int rb = row - b * NL;      // rows row..row+3 never straddle 928
        const int vtrow = (b * NH + (col >> 6)) * HD + (col & 63);
        ushort4 pk4;
        pk4.x = (unsigned short)f2bf(acc[fr][fc][0]);
        pk4.y = (unsigned short)f2bf(acc[fr][fc][1]);
        pk4.z = (unsigned short)f2bf(acc[fr][fc][2]);
        pk4.w = (unsigned short)f2bf(acc[fr][fc][3]);
        *(ushort4*)(o0 + (size_t)vtrow * NL + rb) = pk4;
      }
    }
}

// ---------------------------------------------------------------------------
// attn_fwd v4: flash attention, no-max softmax, block-shared LDS K/V tiles.
// (unchanged)
// ---------------------------------------------------------------------------
__global__ __launch_bounds__(256, 4) void attn_fwd(
    const short* __restrict__ qb, const short* __restrict__ kbuf,
    const short* __restrict__ vtb, short* __restrict__ ob) {
  __shared__ short smem[2][4096];   // per buf: K [32][64] @0, V^T [64][32] @2048
  const int tid = threadIdx.x;
  const int w = tid >> 6;           // wave 0..3
  const int l = tid & 63;
  const int c = l & 15, g = l >> 4;
  const int swzb = (blockIdx.x & 7) * 224 + (blockIdx.x >> 3);
  const int bh = swzb / 7;
  const int blk7 = swzb - bh * 7;
  const int h = bh & 15, b = bh >> 4;
  const int q0 = blk7 * 128 + w * 32;
  const bool active = q0 < NN;

  const int u = l >> 3;                    // 0..7
  const int lK = 8 * w + u;                // LDS K row
  const int b16 = lK & 15;
  const int rpK = 8 * (b16 >> 2) + (b16 & 3) + 4 * (lK >> 4);
  const int xK = (l & 7) ^ u;
  const short* srcK = kbuf + (size_t)b * NL * CC + (size_t)rpK * CC + h * HD + xK * 8;
  const int dV = 16 * w + (l >> 2);
  const int xV = (l & 3) ^ ((l >> 3) & 3);
  const short* srcV = vtb + (size_t)bh * HD * NL + (size_t)dV * NL + xV * 8;

  bf16x8 qf[2][2];
  if (active) {
#pragma unroll
    for (int f = 0; f < 2; ++f) {
      const short* qrow = qb + ((size_t)(b * NL + q0 + f * 16 + c) * CC + h * HD + g * 8);
      qf[f][0] = *(const bf16x8*)qrow;
      qf[f][1] = *(const bf16x8*)(qrow + 32);
    }
  }

  const int koff0 = c * 64 + ((g ^ (c & 7)) << 3);
  const int koff1 = c * 64 + (((g + 4) ^ (c & 7)) << 3);
  const int voffb = 2048 + c * 32 + ((g ^ ((c >> 1) & 3)) << 3);

  f32x4 acc[2][4] = {};
  f32x4 ellv[2] = {};

  GLD_LDS(srcK, &smem[0][w * 512]);
  GLD_LDS(srcV, &smem[0][2048 + w * 512]);
  __syncthreads();

  int buf = 0;
  for (int t = 0; t < 29; ++t) {
    if (t < 28) {
      GLD_LDS(srcK + (size_t)(t + 1) * 32 * CC, &smem[buf ^ 1][w * 512]);
      GLD_LDS(srcV + (t + 1) * 32, &smem[buf ^ 1][2048 + w * 512]);
    }
    if (active) {
      const short* S = smem[buf];
      bf16x8 kd0 = *(const bf16x8*)(S + koff0);
      bf16x8 kd1 = *(const bf16x8*)(S + koff1);
      bf16x8 kd2 = *(const bf16x8*)(S + koff0 + 1024);
      bf16x8 kd3 = *(const bf16x8*)(S + koff1 + 1024);
      bf16x8 vf0 = *(const bf16x8*)(S + voffb);
      bf16x8 vf1 = *(const bf16x8*)(S + voffb + 512);
      bf16x8 vf2 = *(const bf16x8*)(S + voffb + 1024);
      bf16x8 vf3 = *(const bf16x8*)(S + voffb + 1536);
      __builtin_amdgcn_s_setprio(1);
#pragma unroll
      for (int f = 0; f < 2; ++f) {
        f32x4 z = {0.f, 0.f, 0.f, 0.f};
        f32x4 s0 = __builtin_amdgcn_mfma_f32_16x16x32_bf16(kd0, qf[f][0], z, 0, 0, 0);
        s0 = __builtin_amdgcn_mfma_f32_16x16x32_bf16(kd1, qf[f][1], s0, 0, 0, 0);
        f32x4 s1 = __builtin_amdgcn_mfma_f32_16x16x32_bf16(kd2, qf[f][0], z, 0, 0, 0);
        s1 = __builtin_amdgcn_mfma_f32_16x16x32_bf16(kd3, qf[f][1], s1, 0, 0, 0);
        f32x4 e0, e1;
        e0[0] = __builtin_amdgcn_exp2f(s0[0]);
        e0[1] = __builtin_amdgcn_exp2f(s0[1]);
        e0[2] = __builtin_amdgcn_exp2f(s0[2]);
        e0[3] = __builtin_amdgcn_exp2f(s0[3]);
        e1[0] = __builtin_amdgcn_exp2f(s1[0]);
        e1[1] = __builtin_amdgcn_exp2f(s1[1]);
        e1[2] = __builtin_amdgcn_exp2f(s1[2]);
        e1[3] = __builtin_amdgcn_exp2f(s1[3]);
        ellv[f] += e0 + e1;
        union { bf2 h2[4]; bf16x8 v; } pu;
        pu.h2[0] = bf2{(__bf16)e0[0], (__bf16)e0[1]};
        pu.h2[1] = bf2{(__bf16)e0[2], (__bf16)e0[3]};
        pu.h2[2] = bf2{(__bf16)e1[0], (__bf16)e1[1]};
        pu.h2[3] = bf2{(__bf16)e1[2], (__bf16)e1[3]};
        acc[f][0] = __builtin_amdgcn_mfma_f32_16x16x32_bf16(pu.v, vf0, acc[f][0], 0, 0, 0);
        acc[f][1] = __builtin_amdgcn_mfma_f32_16x16x32_bf16(pu.v, vf1, acc[f][1], 0, 0, 0);
        acc[f][2] = __builtin_amdgcn_mfma_f32_16x16x32_bf16(pu.v, vf2, acc[f][2], 0, 0, 0);
        acc[f][3] = __builtin_amdgcn_mfma_f32_16x16x32_bf16(pu.v, vf3, acc[f][3], 0, 0, 0);
      }
      __builtin_amdgcn_s_setprio(0);
    }
    __syncthreads();
    buf ^= 1;
  }

  if (active) {
    float rinv[2];
#pragma unroll
    for (int f = 0; f < 2; ++f) {
      float e = (ellv[f][0] + ellv[f][1]) + (ellv[f][2] + ellv[f][3]);
      e += __shfl_xor(e, 16);
      e += __shfl_xor(e, 32);
      rinv[f] = 1.0f / e;
    }
#pragma unroll
    for (int f = 0; f < 2; ++f) {
      float rj[4];
#pragma unroll
      for (int j = 0; j < 4; ++j) rj[j] = __shfl(rinv[f], g * 4 + j);
      short* orow = ob + (size_t)(b * NN + q0 + f * 16 + g * 4) * CC + h * HD + c;
#pragma unroll
      for (int n = 0; n < 4; ++n)
#pragma unroll
        for (int j = 0; j < 4; ++j)
          orow[(size_t)j * CC + n * 16] = f2bf(acc[f][n][j] * rj[j]);
    }
  }
}

// ---------------------------------------------------------------------------
extern "C" void kernel_launch(void* const* d_in, const int* in_sizes, int n_in,
                              void* d_out, int out_size, void* d_ws, size_t ws_size,
                              hipStream_t stream) {
  const float* x    = (const float*)d_in[0];
  const float* xpos = (const float*)d_in[1];
  const float* k_t  = (const float*)d_in[2];
  const float* v_t  = (const float*)d_in[3];
  const float* Wq   = (const float*)d_in[4];
  const float* Wk   = (const float*)d_in[5];
  const float* Wv   = (const float*)d_in[6];
  const float* Wp   = (const float*)d_in[7];
  const float* bp   = (const float*)d_in[8];
  float* out = (float*)d_out;

  // workspace layout (bytes), total 160,432,128
  char* ws = (char*)d_ws;
  short* k_in = (short*)ws;                       // 30,408,704  [16*928,1024] bf16
  short* v_in = (short*)(ws + 30408704);          // 30,408,704
  short* wqb  = (short*)(ws + 60817408);          // 4 x 2,097,152 (Wq|Wk|Wv|Wp)
  short* wvb  = (short*)(ws + 65011712);
  short* wpb  = (short*)(ws + 67108864);
  short* qbuf = (short*)(ws + 69206016);          // 30,408,704
  short* kbuf = (short*)(ws + 99614720);          // 30,408,704
  short* vtb  = (short*)(ws + 130023424);         // 30,408,704  vt[(b*16+h)*64+d][928]
  short* attn_o = k_in;   // alias: k_in dead after fused qk GEMM

  prep_kv<<<7424, 256, 0, stream>>>(x, xpos, k_t, v_t, k_in, v_in);
  prep_w<<<2048, 256, 0, stream>>>(Wq, Wk, Wv, Wp, wqb);
  // fused q|k projection: Bw = [Wq_scaled ; Wk] (2048 rows, contiguous in ws)
  gemm256<2><<<464, 512, 0, stream>>>(k_in, wqb, qbuf, kbuf, nullptr, nullptr);
  // v projection with fused transpose into vt
  gemm256<3><<<232, 512, 0, stream>>>(v_in, wvb, vtb, nullptr, nullptr, nullptr);
  attn_fwd<<<1792, 256, 0, stream>>>(qbuf, kbuf, vtb, attn_o);
  gemm256<1><<<200, 512, 0, stream>>>(attn_o, wpb, nullptr, nullptr, out, bp);
}

// Round 9
// 261.939 us; speedup vs baseline: 1.2129x; 1.2104x over previous
//
#include <hip/hip_runtime.h>
#include <hip/hip_bf16.h>

// Problem constants
#define NB 16
#define NN 800
#define NCACHE 128
#define NL 928      // NN + NCACHE
#define CC 1024
#define NH 16
#define HD 64

typedef __attribute__((ext_vector_type(8))) short bf16x8;
typedef __attribute__((ext_vector_type(4))) float f32x4;
typedef __attribute__((ext_vector_type(2))) __bf16 bf2;

__device__ __forceinline__ short f2bf(float x) {
  union { float f; unsigned u; } c; c.f = x;
  unsigned r = c.u + 0x7fffu + ((c.u >> 16) & 1u);
  return (short)(r >> 16);
}

#define GLD_LDS(gp, lp) __builtin_amdgcn_global_load_lds( \
    (__attribute__((address_space(1))) void*)(gp),        \
    (__attribute__((address_space(3))) void*)(lp), 16, 0, 0)

#define BAR() asm volatile("s_barrier" ::: "memory")

// ---------------------------------------------------------------------------
// prep_kv: k_in = bf16(concat(x+xpos, k_t)); v_in = bf16(concat(x, v_t))
// ---------------------------------------------------------------------------
__global__ __launch_bounds__(256) void prep_kv(
    const float* __restrict__ x, const float* __restrict__ xpos,
    const float* __restrict__ ktc, const float* __restrict__ vtc,
    short* __restrict__ k_in, short* __restrict__ v_in) {
  int idx = blockIdx.x * 256 + threadIdx.x;   // 0 .. 16*928*128-1
  int chunk = idx & 127;
  int row = idx >> 7;                          // 0..14847
  int b = row / NL;
  int lr = row - b * NL;
  int c = chunk * 8;
  float vk[8], vv[8];
  if (lr < NN) {
    const float4* px = (const float4*)(x + ((size_t)(b * NN + lr) * CC + c));
    const float4* pp = (const float4*)(xpos + ((size_t)(b * NN + lr) * CC + c));
    float4 x0 = px[0], x1 = px[1], p0 = pp[0], p1 = pp[1];
    vv[0]=x0.x; vv[1]=x0.y; vv[2]=x0.z; vv[3]=x0.w;
    vv[4]=x1.x; vv[5]=x1.y; vv[6]=x1.z; vv[7]=x1.w;
    vk[0]=x0.x+p0.x; vk[1]=x0.y+p0.y; vk[2]=x0.z+p0.z; vk[3]=x0.w+p0.w;
    vk[4]=x1.x+p1.x; vk[5]=x1.y+p1.y; vk[6]=x1.z+p1.z; vk[7]=x1.w+p1.w;
  } else {
    const float4* pk = (const float4*)(ktc + ((size_t)(b * NCACHE + lr - NN) * CC + c));
    const float4* pv = (const float4*)(vtc + ((size_t)(b * NCACHE + lr - NN) * CC + c));
    float4 k0 = pk[0], k1 = pk[1], v0 = pv[0], v1 = pv[1];
    vk[0]=k0.x; vk[1]=k0.y; vk[2]=k0.z; vk[3]=k0.w;
    vk[4]=k1.x; vk[5]=k1.y; vk[6]=k1.z; vk[7]=k1.w;
    vv[0]=v0.x; vv[1]=v0.y; vv[2]=v0.z; vv[3]=v0.w;
    vv[4]=v1.x; vv[5]=v1.y; vv[6]=v1.z; vv[7]=v1.w;
  }
  bf16x8 ok, ov;
#pragma unroll
  for (int i = 0; i < 8; ++i) { ok[i] = f2bf(vk[i]); ov[i] = f2bf(vv[i]); }
  *(bf16x8*)(k_in + (size_t)row * CC + c) = ok;
  *(bf16x8*)(v_in + (size_t)row * CC + c) = ov;
}

// ---------------------------------------------------------------------------
// prep_w v2: weights -> bf16 in MFMA-FRAGMENT-PACKED layout so the GEMM's
// B-loads are single coalesced 1KB reads.
//   packed[((t*NF + nf)*2 + ks)*512 + l*8 + j] =
//       W[nf*16 + (l&15)][t*64 + ks*32 + (l>>4)*8 + j]
// Buffers: qk-fused (NF=128: cols<1024 Wq*scale, else Wk), Wv (NF=64),
// Wp (NF=64) — contiguous, so dst offset = global idx*8.
// ---------------------------------------------------------------------------
__global__ __launch_bounds__(256) void prep_w(
    const float* __restrict__ Wq, const float* __restrict__ Wk,
    const float* __restrict__ Wv, const float* __restrict__ Wp,
    short* __restrict__ wout) {
  int idx = blockIdx.x * 256 + threadIdx.x;  // 0..524287
  int l = idx & 63;
  int frag = idx >> 6;                        // 0..8191
  const float* src;
  int col, t, ks;
  float sc = 1.0f;
  if (frag < 4096) {            // qk packed, NF=128
    ks = frag & 1; int nf = (frag >> 1) & 127; t = frag >> 8;
    col = nf * 16 + (l & 15);
    if (col < 1024) { src = Wq; sc = 0.18033688011112042f; }  // 0.125*log2(e)
    else            { src = Wk; col -= 1024; }
  } else if (frag < 6144) {     // Wv packed, NF=64
    int f2 = frag - 4096; ks = f2 & 1; int nf = (f2 >> 1) & 63; t = f2 >> 7;
    col = nf * 16 + (l & 15); src = Wv;
  } else {                      // Wp packed, NF=64
    int f2 = frag - 6144; ks = f2 & 1; int nf = (f2 >> 1) & 63; t = f2 >> 7;
    col = nf * 16 + (l & 15); src = Wp;
  }
  int k = t * 64 + ks * 32 + ((l >> 4) << 3);
  const float4* p = (const float4*)(src + (size_t)col * CC + k);
  float4 a = p[0], b = p[1];
  bf16x8 o;
  o[0]=f2bf(a.x*sc); o[1]=f2bf(a.y*sc); o[2]=f2bf(a.z*sc); o[3]=f2bf(a.w*sc);
  o[4]=f2bf(b.x*sc); o[5]=f2bf(b.y*sc); o[6]=f2bf(b.z*sc); o[7]=f2bf(b.w*sc);
  *(bf16x8*)(wout + (size_t)idx * 8) = o;
}

// ---------------------------------------------------------------------------
// gemm256 v4: 256x256 tile, BK=64. A staged in LDS (64 KiB dbuf, XOR-chunk
// swizzle, gload_lds) -> 2 blocks/CU. B streamed from global in the packed
// fragment layout: 8 coalesced 1KB loads/wave/K-tile, L2/L3-resident.
// Per-K-tile LDS traffic 160KB (< MFMA 2484cy floor) vs 256KB when B was
// LDS-staged. vmcnt ledger: [B(t):8 reg loads][stage A(t+1):4 gload_lds]
// [vmcnt(12) -> A(t) landed][BAR][16 A ds_reads + 64 MFMA; compiler waits
// B-regs with vmcnt(4), A(t+1) stays in flight][BAR].
// XCD swizzle bn-fastest: A panel (512KB) reused 8x from each XCD's L2.
// MODE 1: f32 out + bias. MODE 2: qk fused N=2048 (split stores). MODE 3:
// v-projection with fused transpose into vt[(b*16+h)*64+d][928].
// ---------------------------------------------------------------------------
#define READ_A8(dst, QR) \
  _Pragma("unroll") \
  for (int fr = 0; fr < 4; ++fr) \
    _Pragma("unroll") \
    for (int ks = 0; ks < 2; ++ks) \
      dst[fr][ks] = *(const bf16x8*)&lds[abase + (QR)*4096 + fr*1024 + (ks ? xk1 : xk0)];

#define MFMA_HALF(QR, asrc) \
  _Pragma("unroll") \
  for (int fr = 0; fr < 4; ++fr) \
    _Pragma("unroll") \
    for (int fc = 0; fc < 4; ++fc) \
      _Pragma("unroll") \
      for (int ks = 0; ks < 2; ++ks) \
        acc[(QR)*4+fr][fc] = __builtin_amdgcn_mfma_f32_16x16x32_bf16( \
            asrc[fr][ks], bfv[fc][ks], acc[(QR)*4+fr][fc], 0, 0, 0);

template<int MODE>
__global__ __launch_bounds__(512, 2) void gemm256(
    const short* __restrict__ A, const short* __restrict__ Bw,
    short* __restrict__ o0, short* __restrict__ o1,
    float* __restrict__ of, const float* __restrict__ bias) {
  __shared__ short lds[32768];   // 64 KiB: parity p at p*16384 shorts (A only)
  const int tid = threadIdx.x;
  const int w = tid >> 6, l = tid & 63;
  const int wm = w >> 2, wn = w & 3;
  const int c = l & 15, g2 = l >> 4;
  const int BNT = (MODE == 2) ? 8 : 4;
  const int NF  = (MODE == 2) ? 128 : 64;
  const int cpx = gridDim.x >> 3;
  const int swz = (blockIdx.x & 7) * cpx + (blockIdx.x >> 3);
  const int bm = swz / BNT, bn = swz % BNT;   // bn-fastest: A panel L2-reused
  const int m0 = bm * 256, n0 = bn * 256;

  // A staging source (per-lane, chunk-XOR pre-swizzled)
  const int R0 = tid >> 3;                   // 0..63
  const int gc0 = (tid & 7) ^ (R0 & 7);
  const short* As_ = A + (size_t)(m0 + R0) * CC + gc0 * 8;
  const int wofs = w * 512;                  // wave-uniform lds chunk base

#define STAGE_HT(slot, src) do { \
    GLD_LDS((src), &lds[(slot) + wofs]); \
    GLD_LDS((src) + 64 * CC, &lds[(slot) + 4096 + wofs]); } while (0)

  // B packed-fragment base for this wave's 64-col strip
  const int nf0 = (n0 >> 4) + wn * 4;

  // ds_read swizzled k-chunk offsets (shorts)
  const int xk0 = ((g2) ^ (c & 7)) * 8;
  const int xk1 = ((g2 + 4) ^ (c & 7)) * 8;

  f32x4 acc[8][4] = {};

  // prologue: stage A tile 0 into parity 0
  STAGE_HT(0,    As_);
  STAGE_HT(8192, As_ + 128 * CC);

#pragma unroll 1
  for (int t = 0; t < 16; ++t) {
    const int pb = (t & 1) << 14;        // parity holding A tile t
    const int pn = pb ^ 16384;           // parity for tile t+1
    // B(t): 8 coalesced 1KB fragment loads (retire under A ds_read drain)
    bf16x8 bfv[4][2];
    {
      const short* Bpt = Bw + (((size_t)t * NF + nf0) << 10) + (l << 3);
#pragma unroll
      for (int fc = 0; fc < 4; ++fc)
#pragma unroll
        for (int ks = 0; ks < 2; ++ks)
          bfv[fc][ks] = *(const bf16x8*)(Bpt + ((fc << 1) | ks) * 512);
    }
    if (t < 15) {
      const short* as1 = As_ + (t + 1) * 64;
      STAGE_HT(pn,        as1);
      STAGE_HT(pn + 8192, as1 + 128 * CC);
      // outstanding: A(t):4 oldest + B(t):8 + A(t+1):4 -> retires A(t)
      asm volatile("s_waitcnt vmcnt(12)" ::: "memory");
    } else {
      // outstanding: A(15):4 oldest + B(15):8
      asm volatile("s_waitcnt vmcnt(8)" ::: "memory");
    }
    BAR();   // cross-wave: A tile t fully visible
    const int abase = pb + wm * 8192 + c * 64;
    bf16x8 afA[4][2], afB[4][2];
    READ_A8(afA, 0);
    __builtin_amdgcn_s_setprio(1);
    MFMA_HALF(0, afA);
    __builtin_amdgcn_s_setprio(0);
    READ_A8(afB, 1);
    __builtin_amdgcn_s_setprio(1);
    MFMA_HALF(1, afB);
    __builtin_amdgcn_s_setprio(0);
    BAR();   // all waves consumed parity pb -> next iter may stage into it
  }

  // epilogue
#pragma unroll
  for (int fr = 0; fr < 8; ++fr)
#pragma unroll
    for (int fc = 0; fc < 4; ++fc) {
      const int row = m0 + wm * 128 + fr * 16 + g2 * 4;
      const int colw = wn * 64 + fc * 16 + c;
      if (MODE == 1) {
        const int col = n0 + colw;
        const float bv = bias[col];
#pragma unroll
        for (int j = 0; j < 4; ++j)
          of[(size_t)(row + j) * CC + col] = acc[fr][fc][j] + bv;
      } else if (MODE == 2) {
        const int col2 = n0 + colw;
        short* base = (col2 < 1024) ? o0 : o1;
        const int col = col2 & 1023;
#pragma unroll
        for (int j = 0; j < 4; ++j)
          base[(size_t)(row + j) * CC + col] = f2bf(acc[fr][fc][j]);
      } else {  // MODE 3: transposed store into vt[(b*16+h)*64+d][NL]
        const int col = n0 + colw;
        const int b = row / NL;
        const int rb = row - b * NL;      // rows row..row+3 never straddle 928
        const int vtrow = (b * NH + (col >> 6)) * HD + (col & 63);
        ushort4 pk4;
        pk4.x = (unsigned short)f2bf(acc[fr][fc][0]);
        pk4.y = (unsigned short)f2bf(acc[fr][fc][1]);
        pk4.z = (unsigned short)f2bf(acc[fr][fc][2]);
        pk4.w = (unsigned short)f2bf(acc[fr][fc][3]);
        *(ushort4*)(o0 + (size_t)vtrow * NL + rb) = pk4;
      }
    }
}

// ---------------------------------------------------------------------------
// attn_fwd v4: flash attention, no-max softmax, block-shared LDS K/V tiles.
// (unchanged)
// ---------------------------------------------------------------------------
__global__ __launch_bounds__(256, 4) void attn_fwd(
    const short* __restrict__ qb, const short* __restrict__ kbuf,
    const short* __restrict__ vtb, short* __restrict__ ob) {
  __shared__ short smem[2][4096];   // per buf: K [32][64] @0, V^T [64][32] @2048
  const int tid = threadIdx.x;
  const int w = tid >> 6;           // wave 0..3
  const int l = tid & 63;
  const int c = l & 15, g = l >> 4;
  const int swzb = (blockIdx.x & 7) * 224 + (blockIdx.x >> 3);
  const int bh = swzb / 7;
  const int blk7 = swzb - bh * 7;
  const int h = bh & 15, b = bh >> 4;
  const int q0 = blk7 * 128 + w * 32;
  const bool active = q0 < NN;

  const int u = l >> 3;                    // 0..7
  const int lK = 8 * w + u;                // LDS K row
  const int b16 = lK & 15;
  const int rpK = 8 * (b16 >> 2) + (b16 & 3) + 4 * (lK >> 4);
  const int xK = (l & 7) ^ u;
  const short* srcK = kbuf + (size_t)b * NL * CC + (size_t)rpK * CC + h * HD + xK * 8;
  const int dV = 16 * w + (l >> 2);
  const int xV = (l & 3) ^ ((l >> 3) & 3);
  const short* srcV = vtb + (size_t)bh * HD * NL + (size_t)dV * NL + xV * 8;

  bf16x8 qf[2][2];
  if (active) {
#pragma unroll
    for (int f = 0; f < 2; ++f) {
      const short* qrow = qb + ((size_t)(b * NL + q0 + f * 16 + c) * CC + h * HD + g * 8);
      qf[f][0] = *(const bf16x8*)qrow;
      qf[f][1] = *(const bf16x8*)(qrow + 32);
    }
  }

  const int koff0 = c * 64 + ((g ^ (c & 7)) << 3);
  const int koff1 = c * 64 + (((g + 4) ^ (c & 7)) << 3);
  const int voffb = 2048 + c * 32 + ((g ^ ((c >> 1) & 3)) << 3);

  f32x4 acc[2][4] = {};
  f32x4 ellv[2] = {};

  GLD_LDS(srcK, &smem[0][w * 512]);
  GLD_LDS(srcV, &smem[0][2048 + w * 512]);
  __syncthreads();

  int buf = 0;
  for (int t = 0; t < 29; ++t) {
    if (t < 28) {
      GLD_LDS(srcK + (size_t)(t + 1) * 32 * CC, &smem[buf ^ 1][w * 512]);
      GLD_LDS(srcV + (t + 1) * 32, &smem[buf ^ 1][2048 + w * 512]);
    }
    if (active) {
      const short* S = smem[buf];
      bf16x8 kd0 = *(const bf16x8*)(S + koff0);
      bf16x8 kd1 = *(const bf16x8*)(S + koff1);
      bf16x8 kd2 = *(const bf16x8*)(S + koff0 + 1024);
      bf16x8 kd3 = *(const bf16x8*)(S + koff1 + 1024);
      bf16x8 vf0 = *(const bf16x8*)(S + voffb);
      bf16x8 vf1 = *(const bf16x8*)(S + voffb + 512);
      bf16x8 vf2 = *(const bf16x8*)(S + voffb + 1024);
      bf16x8 vf3 = *(const bf16x8*)(S + voffb + 1536);
      __builtin_amdgcn_s_setprio(1);
#pragma unroll
      for (int f = 0; f < 2; ++f) {
        f32x4 z = {0.f, 0.f, 0.f, 0.f};
        f32x4 s0 = __builtin_amdgcn_mfma_f32_16x16x32_bf16(kd0, qf[f][0], z, 0, 0, 0);
        s0 = __builtin_amdgcn_mfma_f32_16x16x32_bf16(kd1, qf[f][1], s0, 0, 0, 0);
        f32x4 s1 = __builtin_amdgcn_mfma_f32_16x16x32_bf16(kd2, qf[f][0], z, 0, 0, 0);
        s1 = __builtin_amdgcn_mfma_f32_16x16x32_bf16(kd3, qf[f][1], s1, 0, 0, 0);
        f32x4 e0, e1;
        e0[0] = __builtin_amdgcn_exp2f(s0[0]);
        e0[1] = __builtin_amdgcn_exp2f(s0[1]);
        e0[2] = __builtin_amdgcn_exp2f(s0[2]);
        e0[3] = __builtin_amdgcn_exp2f(s0[3]);
        e1[0] = __builtin_amdgcn_exp2f(s1[0]);
        e1[1] = __builtin_amdgcn_exp2f(s1[1]);
        e1[2] = __builtin_amdgcn_exp2f(s1[2]);
        e1[3] = __builtin_amdgcn_exp2f(s1[3]);
        ellv[f] += e0 + e1;
        union { bf2 h2[4]; bf16x8 v; } pu;
        pu.h2[0] = bf2{(__bf16)e0[0], (__bf16)e0[1]};
        pu.h2[1] = bf2{(__bf16)e0[2], (__bf16)e0[3]};
        pu.h2[2] = bf2{(__bf16)e1[0], (__bf16)e1[1]};
        pu.h2[3] = bf2{(__bf16)e1[2], (__bf16)e1[3]};
        acc[f][0] = __builtin_amdgcn_mfma_f32_16x16x32_bf16(pu.v, vf0, acc[f][0], 0, 0, 0);
        acc[f][1] = __builtin_amdgcn_mfma_f32_16x16x32_bf16(pu.v, vf1, acc[f][1], 0, 0, 0);
        acc[f][2] = __builtin_amdgcn_mfma_f32_16x16x32_bf16(pu.v, vf2, acc[f][2], 0, 0, 0);
        acc[f][3] = __builtin_amdgcn_mfma_f32_16x16x32_bf16(pu.v, vf3, acc[f][3], 0, 0, 0);
      }
      __builtin_amdgcn_s_setprio(0);
    }
    __syncthreads();
    buf ^= 1;
  }

  if (active) {
    float rinv[2];
#pragma unroll
    for (int f = 0; f < 2; ++f) {
      float e = (ellv[f][0] + ellv[f][1]) + (ellv[f][2] + ellv[f][3]);
      e += __shfl_xor(e, 16);
      e += __shfl_xor(e, 32);
      rinv[f] = 1.0f / e;
    }
#pragma unroll
    for (int f = 0; f < 2; ++f) {
      float rj[4];
#pragma unroll
      for (int j = 0; j < 4; ++j) rj[j] = __shfl(rinv[f], g * 4 + j);
      short* orow = ob + (size_t)(b * NN + q0 + f * 16 + g * 4) * CC + h * HD + c;
#pragma unroll
      for (int n = 0; n < 4; ++n)
#pragma unroll
        for (int j = 0; j < 4; ++j)
          orow[(size_t)j * CC + n * 16] = f2bf(acc[f][n][j] * rj[j]);
    }
  }
}

// ---------------------------------------------------------------------------
extern "C" void kernel_launch(void* const* d_in, const int* in_sizes, int n_in,
                              void* d_out, int out_size, void* d_ws, size_t ws_size,
                              hipStream_t stream) {
  const float* x    = (const float*)d_in[0];
  const float* xpos = (const float*)d_in[1];
  const float* k_t  = (const float*)d_in[2];
  const float* v_t  = (const float*)d_in[3];
  const float* Wq   = (const float*)d_in[4];
  const float* Wk   = (const float*)d_in[5];
  const float* Wv   = (const float*)d_in[6];
  const float* Wp   = (const float*)d_in[7];
  const float* bp   = (const float*)d_in[8];
  float* out = (float*)d_out;

  // workspace layout (bytes), total 160,432,128
  char* ws = (char*)d_ws;
  short* k_in = (short*)ws;                       // 30,408,704  [16*928,1024] bf16
  short* v_in = (short*)(ws + 30408704);          // 30,408,704
  short* wqb  = (short*)(ws + 60817408);          // packed qk-fused, 4 MB
  short* wvb  = (short*)(ws + 65011712);          // packed Wv, 2 MB
  short* wpb  = (short*)(ws + 67108864);          // packed Wp, 2 MB
  short* qbuf = (short*)(ws + 69206016);          // 30,408,704
  short* kbuf = (short*)(ws + 99614720);          // 30,408,704
  short* vtb  = (short*)(ws + 130023424);         // 30,408,704  vt[(b*16+h)*64+d][928]
  short* attn_o = k_in;   // alias: k_in dead after fused qk GEMM

  prep_kv<<<7424, 256, 0, stream>>>(x, xpos, k_t, v_t, k_in, v_in);
  prep_w<<<2048, 256, 0, stream>>>(Wq, Wk, Wv, Wp, wqb);
  // fused q|k projection (packed B, N=2048)
  gemm256<2><<<464, 512, 0, stream>>>(k_in, wqb, qbuf, kbuf, nullptr, nullptr);
  // v projection with fused transpose into vt (packed B)
  gemm256<3><<<232, 512, 0, stream>>>(v_in, wvb, vtb, nullptr, nullptr, nullptr);
  attn_fwd<<<1792, 256, 0, stream>>>(qbuf, kbuf, vtb, attn_o);
  gemm256<1><<<200, 512, 0, stream>>>(attn_o, wpb, nullptr, nullptr, out, bp);
}

// Round 11
// 246.984 us; speedup vs baseline: 1.2864x; 1.0605x over previous
//
#include <hip/hip_runtime.h>
#include <hip/hip_bf16.h>

// Problem constants
#define NB 16
#define NN 800
#define NCACHE 128
#define NL 928      // NN + NCACHE
#define CC 1024
#define NH 16
#define HD 64

typedef __attribute__((ext_vector_type(8))) short bf16x8;
typedef __attribute__((ext_vector_type(4))) float f32x4;
typedef __attribute__((ext_vector_type(2))) __bf16 bf2;

__device__ __forceinline__ short f2bf(float x) {
  union { float f; unsigned u; } c; c.f = x;
  unsigned r = c.u + 0x7fffu + ((c.u >> 16) & 1u);
  return (short)(r >> 16);
}

#define GLD_LDS(gp, lp) __builtin_amdgcn_global_load_lds( \
    (__attribute__((address_space(1))) void*)(gp),        \
    (__attribute__((address_space(3))) void*)(lp), 16, 0, 0)

#define BAR() asm volatile("s_barrier" ::: "memory")

// ---------------------------------------------------------------------------
// prep_kv: k_in = bf16(concat(x+xpos, k_t)); v_in = bf16(concat(x, v_t))
// ---------------------------------------------------------------------------
__global__ __launch_bounds__(256) void prep_kv(
    const float* __restrict__ x, const float* __restrict__ xpos,
    const float* __restrict__ ktc, const float* __restrict__ vtc,
    short* __restrict__ k_in, short* __restrict__ v_in) {
  int idx = blockIdx.x * 256 + threadIdx.x;   // 0 .. 16*928*128-1
  int chunk = idx & 127;
  int row = idx >> 7;                          // 0..14847
  int b = row / NL;
  int lr = row - b * NL;
  int c = chunk * 8;
  float vk[8], vv[8];
  if (lr < NN) {
    const float4* px = (const float4*)(x + ((size_t)(b * NN + lr) * CC + c));
    const float4* pp = (const float4*)(xpos + ((size_t)(b * NN + lr) * CC + c));
    float4 x0 = px[0], x1 = px[1], p0 = pp[0], p1 = pp[1];
    vv[0]=x0.x; vv[1]=x0.y; vv[2]=x0.z; vv[3]=x0.w;
    vv[4]=x1.x; vv[5]=x1.y; vv[6]=x1.z; vv[7]=x1.w;
    vk[0]=x0.x+p0.x; vk[1]=x0.y+p0.y; vk[2]=x0.z+p0.z; vk[3]=x0.w+p0.w;
    vk[4]=x1.x+p1.x; vk[5]=x1.y+p1.y; vk[6]=x1.z+p1.z; vk[7]=x1.w+p1.w;
  } else {
    const float4* pk = (const float4*)(ktc + ((size_t)(b * NCACHE + lr - NN) * CC + c));
    const float4* pv = (const float4*)(vtc + ((size_t)(b * NCACHE + lr - NN) * CC + c));
    float4 k0 = pk[0], k1 = pk[1], v0 = pv[0], v1 = pv[1];
    vk[0]=k0.x; vk[1]=k0.y; vk[2]=k0.z; vk[3]=k0.w;
    vk[4]=k1.x; vk[5]=k1.y; vk[6]=k1.z; vk[7]=k1.w;
    vv[0]=v0.x; vv[1]=v0.y; vv[2]=v0.z; vv[3]=v0.w;
    vv[4]=v1.x; vv[5]=v1.y; vv[6]=v1.z; vv[7]=v1.w;
  }
  bf16x8 ok, ov;
#pragma unroll
  for (int i = 0; i < 8; ++i) { ok[i] = f2bf(vk[i]); ov[i] = f2bf(vv[i]); }
  *(bf16x8*)(k_in + (size_t)row * CC + c) = ok;
  *(bf16x8*)(v_in + (size_t)row * CC + c) = ov;
}

// ---------------------------------------------------------------------------
// prep_w v1: 4 weights -> bf16 contiguous rows; Wq scaled by HD^-0.5*log2(e).
// ---------------------------------------------------------------------------
__global__ __launch_bounds__(256) void prep_w(
    const float* __restrict__ Wq, const float* __restrict__ Wk,
    const float* __restrict__ Wv, const float* __restrict__ Wp,
    short* __restrict__ wout) {
  int idx = blockIdx.x * 256 + threadIdx.x;  // 0..524287
  int wsel = idx >> 17;
  int off = (idx & 131071) * 8;
  const float* src = wsel == 0 ? Wq : wsel == 1 ? Wk : wsel == 2 ? Wv : Wp;
  float sc = wsel == 0 ? 0.18033688011112042f : 1.0f;  // 0.125 * log2(e)
  const float4* p = (const float4*)(src + off);
  float4 a = p[0], b = p[1];
  bf16x8 o;
  o[0]=f2bf(a.x*sc); o[1]=f2bf(a.y*sc); o[2]=f2bf(a.z*sc); o[3]=f2bf(a.w*sc);
  o[4]=f2bf(b.x*sc); o[5]=f2bf(b.y*sc); o[6]=f2bf(b.z*sc); o[7]=f2bf(b.w*sc);
  *(bf16x8*)(wout + (size_t)wsel * 1048576 + off) = o;
}

// ---------------------------------------------------------------------------
// gemm256 v2 (r6, known-good): 256x256 tile, BK=64, 2-barrier pipelined loop.
// A+B staged in LDS (128 KiB dbuf, 16B-chunk XOR swizzle, gload_lds).
// Per K-tile: [stage t+1: 8 gload_lds][vmcnt(8)][BAR][24 ds_read + 64 MFMA]
// [BAR]. MODE 1: f32+bias. MODE 2: qk fused N=2048. MODE 3: v + fused
// transpose into vt[(b*16+h)*64+d][928].
// ---------------------------------------------------------------------------
#define READ_A8(dst, QR) \
  _Pragma("unroll") \
  for (int fr = 0; fr < 4; ++fr) \
    _Pragma("unroll") \
    for (int ks = 0; ks < 2; ++ks) \
      dst[fr][ks] = *(const bf16x8*)&lds[abase + (QR)*4096 + fr*1024 + (ks ? xk1 : xk0)];

#define READ_B8() \
  _Pragma("unroll") \
  for (int q = 0; q < 4; ++q) \
    _Pragma("unroll") \
    for (int ks = 0; ks < 2; ++ks) \
      bfv[q][ks] = *(const bf16x8*)&lds[bbase + q*1024 + (ks ? xk1 : xk0)];

#define MFMA_HALF(QR, asrc) \
  _Pragma("unroll") \
  for (int fr = 0; fr < 4; ++fr) \
    _Pragma("unroll") \
    for (int fc = 0; fc < 4; ++fc) \
      _Pragma("unroll") \
      for (int ks = 0; ks < 2; ++ks) \
        acc[(QR)*4+fr][fc] = __builtin_amdgcn_mfma_f32_16x16x32_bf16( \
            asrc[fr][ks], bfv[fc][ks], acc[(QR)*4+fr][fc], 0, 0, 0);

template<int MODE>
__global__ __launch_bounds__(512, 2) void gemm256(
    const short* __restrict__ A, const short* __restrict__ Bw,
    short* __restrict__ o0, short* __restrict__ o1,
    float* __restrict__ of, const float* __restrict__ bias) {
  __shared__ short lds[65536];   // 128 KiB: parity p at p*32768; A @+0, B @+16384
  const int tid = threadIdx.x;
  const int w = tid >> 6, l = tid & 63;
  const int wm = w >> 2, wn = w & 3;
  const int c = l & 15, g2 = l >> 4;
  const int BNT = (MODE == 2) ? 8 : 4;
  const int cpx = gridDim.x >> 3;
  const int swz = (blockIdx.x & 7) * cpx + (blockIdx.x >> 3);
  const int bm = swz / BNT, bn = swz % BNT;
  const int m0 = bm * 256, n0 = bn * 256;

  const int R0 = tid >> 3;                   // 0..63
  const int gc0 = (tid & 7) ^ (R0 & 7);
  const short* As_ = A + (size_t)(m0 + R0) * CC + gc0 * 8;
  const short* Bs_ = Bw + (size_t)(n0 + R0) * CC + gc0 * 8;
  const int wofs = w * 512;                  // wave-uniform lds chunk base

#define STAGE_HT(slot, src) do { \
    GLD_LDS((src), &lds[(slot) + wofs]); \
    GLD_LDS((src) + 64 * CC, &lds[(slot) + 4096 + wofs]); } while (0)

  const int xk0 = ((g2) ^ (c & 7)) * 8;
  const int xk1 = ((g2 + 4) ^ (c & 7)) * 8;

  f32x4 acc[8][4] = {};

  // prologue: stage tile 0 into parity 0
  STAGE_HT(0,     As_);
  STAGE_HT(8192,  As_ + 128 * CC);
  STAGE_HT(16384, Bs_);
  STAGE_HT(24576, Bs_ + 128 * CC);

#pragma unroll 1
  for (int t = 0; t < 16; ++t) {
    const int pb = (t & 1) << 15;        // parity holding tile t
    const int pn = pb ^ 32768;           // parity for tile t+1
    if (t < 15) {
      const short* as1 = As_ + (t + 1) * 64;
      const short* bs1 = Bs_ + (t + 1) * 64;
      STAGE_HT(pn,         as1);
      STAGE_HT(pn + 8192,  as1 + 128 * CC);
      STAGE_HT(pn + 16384, bs1);
      STAGE_HT(pn + 24576, bs1 + 128 * CC);
      asm volatile("s_waitcnt vmcnt(8)" ::: "memory");   // tile t landed; t+1 in flight
    } else {
      asm volatile("s_waitcnt vmcnt(0)" ::: "memory");
    }
    BAR();   // cross-wave: tile t fully visible
    const int abase = pb + wm * 8192 + c * 64;
    const int bbase = pb + 16384 + ((wn >> 1) << 13) + ((wn & 1) * 64 + c) * 64;
    bf16x8 afA[4][2], afB[4][2], bfv[4][2];
    READ_A8(afA, 0);
    READ_B8();
    __builtin_amdgcn_s_setprio(1);
    MFMA_HALF(0, afA);
    __builtin_amdgcn_s_setprio(0);
    READ_A8(afB, 1);
    __builtin_amdgcn_s_setprio(1);
    MFMA_HALF(1, afB);
    __builtin_amdgcn_s_setprio(0);
    BAR();   // all waves consumed parity pb -> next iter may stage into it
  }

  // epilogue
#pragma unroll
  for (int fr = 0; fr < 8; ++fr)
#pragma unroll
    for (int fc = 0; fc < 4; ++fc) {
      const int row = m0 + wm * 128 + fr * 16 + g2 * 4;
      const int colw = wn * 64 + fc * 16 + c;
      if (MODE == 1) {
        const int col = n0 + colw;
        const float bv = bias[col];
#pragma unroll
        for (int j = 0; j < 4; ++j)
          of[(size_t)(row + j) * CC + col] = acc[fr][fc][j] + bv;
      } else if (MODE == 2) {
        const int col2 = n0 + colw;
        short* base = (col2 < 1024) ? o0 : o1;
        const int col = col2 & 1023;
#pragma unroll
        for (int j = 0; j < 4; ++j)
          base[(size_t)(row + j) * CC + col] = f2bf(acc[fr][fc][j]);
      } else {  // MODE 3: transposed store into vt[(b*16+h)*64+d][NL]
        const int col = n0 + colw;
        const int b = row / NL;
        const int rb = row - b * NL;      // rows row..row+3 never straddle 928
        const int vtrow = (b * NH + (col >> 6)) * HD + (col & 63);
        ushort4 pk4;
        pk4.x = (unsigned short)f2bf(acc[fr][fc][0]);
        pk4.y = (unsigned short)f2bf(acc[fr][fc][1]);
        pk4.z = (unsigned short)f2bf(acc[fr][fc][2]);
        pk4.w = (unsigned short)f2bf(acc[fr][fc][3]);
        *(ushort4*)(o0 + (size_t)vtrow * NL + rb) = pk4;
      }
    }
}

// ---------------------------------------------------------------------------
// attn_fwd v5.1: KVBLK=64 (15 sync rounds vs 29). 4 waves/block x 32 q-rows,
// no-max softmax; K row-permuted (A-frag order) + chunk-XOR swizzle; V^T
// likewise. LDS 32KB dbuf. All sync via __syncthreads() (full vmcnt drain).
// Tail (928 = 14*64 + 32): UNIFORM-EXEC staging — V chunks whose global col
// would exceed 928 are clamped in-bounds (garbage data, provably never read:
// reads only touch swizzle slots mapping to global chunks 0..3).
// ---------------------------------------------------------------------------
__global__ __launch_bounds__(256, 3) void attn_fwd(
    const short* __restrict__ qb, const short* __restrict__ kbuf,
    const short* __restrict__ vtb, short* __restrict__ ob) {
  __shared__ short smem[2][8192];   // per buf: K [64][64] @0, V^T [64][64] @4096
  const int tid = threadIdx.x;
  const int w = tid >> 6;           // wave 0..3
  const int l = tid & 63;
  const int c = l & 15, g = l >> 4;
  const int swzb = (blockIdx.x & 7) * 224 + (blockIdx.x >> 3);
  const int bh = swzb / 7;
  const int blk7 = swzb - bh * 7;
  const int h = bh & 15, b = bh >> 4;
  const int q0 = blk7 * 128 + w * 32;
  const bool active = q0 < NN;

  // staging lanes: r = row-within-32, ch = 16B chunk (8/row)
  const int r = tid >> 3, ch = tid & 7;
  const int b16 = r & 15;
  const int rp = 8 * (b16 >> 2) + (b16 & 3) + 4 * (r >> 4);  // perm within 32
  const int xch = ch ^ (r & 7);
  const int tid8 = tid * 8;
  const short* srcKA = kbuf + (size_t)(b * NL + rp) * CC + h * HD + xch * 8;
  const short* srcVA = vtb + (size_t)(bh * HD + r) * NL + xch * 8;
  const short* srcVB = vtb + (size_t)(bh * HD + 32 + r) * NL + xch * 8;

  bf16x8 qf[2][2];
  if (active) {
#pragma unroll
    for (int f = 0; f < 2; ++f) {
      const short* qrow = qb + ((size_t)(b * NL + q0 + f * 16 + c) * CC + h * HD + g * 8);
      qf[f][0] = *(const bf16x8*)qrow;
      qf[f][1] = *(const bf16x8*)(qrow + 32);
    }
  }

  // read chunk offsets: global chunk (ks*4+g) ^ (row&7), row&7 == c&7
  int xrc[2];
#pragma unroll
  for (int ks = 0; ks < 2; ++ks)
    xrc[ks] = (((ks * 4 + g) ^ (c & 7)) << 3);

  f32x4 acc[2][4] = {};
  f32x4 ellv[2] = {};

  auto STG_FULL = [&](int buf, int t) {
    GLD_LDS(srcKA + (size_t)(t * 64) * CC,      &smem[buf][tid8]);
    GLD_LDS(srcKA + (size_t)(t * 64 + 32) * CC, &smem[buf][2048 + tid8]);
    GLD_LDS(srcVA + t * 64,                     &smem[buf][4096 + tid8]);
    GLD_LDS(srcVB + t * 64,                     &smem[buf][6144 + tid8]);
  };
  auto STG_TAIL = [&](int buf) {
    GLD_LDS(srcKA + (size_t)896 * CC, &smem[buf][tid8]);   // kv 896+rp
    // uniform exec: chunks with global col >= 928 clamp back 32 cols
    // (in-bounds garbage; never read — reads use global chunks 0..3 only)
    const int voff = (xch < 4) ? 896 : 864;
    GLD_LDS(srcVA + voff, &smem[buf][4096 + tid8]);
    GLD_LDS(srcVB + voff, &smem[buf][6144 + tid8]);
  };

  auto COMP_FULL = [&](const short* S) {
    bf16x8 kd[4][2], vf[4][2];
#pragma unroll
    for (int si = 0; si < 4; ++si)
#pragma unroll
      for (int ks = 0; ks < 2; ++ks)
        kd[si][ks] = *(const bf16x8*)&S[si * 1024 + c * 64 + xrc[ks]];
#pragma unroll
    for (int n = 0; n < 4; ++n)
#pragma unroll
      for (int ks = 0; ks < 2; ++ks)
        vf[n][ks] = *(const bf16x8*)&S[4096 + (n * 16 + c) * 64 + xrc[ks]];
    __builtin_amdgcn_s_setprio(1);
#pragma unroll
    for (int f = 0; f < 2; ++f) {
      f32x4 z = {0.f, 0.f, 0.f, 0.f};
      f32x4 s[4];
#pragma unroll
      for (int si = 0; si < 4; ++si) {
        s[si] = __builtin_amdgcn_mfma_f32_16x16x32_bf16(kd[si][0], qf[f][0], z, 0, 0, 0);
        s[si] = __builtin_amdgcn_mfma_f32_16x16x32_bf16(kd[si][1], qf[f][1], s[si], 0, 0, 0);
      }
      f32x4 e[4];
#pragma unroll
      for (int si = 0; si < 4; ++si)
#pragma unroll
        for (int j = 0; j < 4; ++j)
          e[si][j] = __builtin_amdgcn_exp2f(s[si][j]);
      ellv[f] += (e[0] + e[1]) + (e[2] + e[3]);
      union { bf2 h2[4]; bf16x8 v; } p0, p1;
      p0.h2[0] = bf2{(__bf16)e[0][0], (__bf16)e[0][1]};
      p0.h2[1] = bf2{(__bf16)e[0][2], (__bf16)e[0][3]};
      p0.h2[2] = bf2{(__bf16)e[1][0], (__bf16)e[1][1]};
      p0.h2[3] = bf2{(__bf16)e[1][2], (__bf16)e[1][3]};
      p1.h2[0] = bf2{(__bf16)e[2][0], (__bf16)e[2][1]};
      p1.h2[1] = bf2{(__bf16)e[2][2], (__bf16)e[2][3]};
      p1.h2[2] = bf2{(__bf16)e[3][0], (__bf16)e[3][1]};
      p1.h2[3] = bf2{(__bf16)e[3][2], (__bf16)e[3][3]};
#pragma unroll
      for (int n = 0; n < 4; ++n) {
        acc[f][n] = __builtin_amdgcn_mfma_f32_16x16x32_bf16(p0.v, vf[n][0], acc[f][n], 0, 0, 0);
        acc[f][n] = __builtin_amdgcn_mfma_f32_16x16x32_bf16(p1.v, vf[n][1], acc[f][n], 0, 0, 0);
      }
    }
    __builtin_amdgcn_s_setprio(0);
  };

  auto COMP_TAIL = [&](const short* S) {
    bf16x8 kd[2][2], vf[4];
#pragma unroll
    for (int si = 0; si < 2; ++si)
#pragma unroll
      for (int ks = 0; ks < 2; ++ks)
        kd[si][ks] = *(const bf16x8*)&S[si * 1024 + c * 64 + xrc[ks]];
#pragma unroll
    for (int n = 0; n < 4; ++n)
      vf[n] = *(const bf16x8*)&S[4096 + (n * 16 + c) * 64 + xrc[0]];
#pragma unroll
    for (int f = 0; f < 2; ++f) {
      f32x4 z = {0.f, 0.f, 0.f, 0.f};
      f32x4 s[2];
#pragma unroll
      for (int si = 0; si < 2; ++si) {
        s[si] = __builtin_amdgcn_mfma_f32_16x16x32_bf16(kd[si][0], qf[f][0], z, 0, 0, 0);
        s[si] = __builtin_amdgcn_mfma_f32_16x16x32_bf16(kd[si][1], qf[f][1], s[si], 0, 0, 0);
      }
      f32x4 e0, e1;
#pragma unroll
      for (int j = 0; j < 4; ++j) { e0[j] = __builtin_amdgcn_exp2f(s[0][j]);
                                    e1[j] = __builtin_amdgcn_exp2f(s[1][j]); }
      ellv[f] += e0 + e1;
      union { bf2 h2[4]; bf16x8 v; } p0;
      p0.h2[0] = bf2{(__bf16)e0[0], (__bf16)e0[1]};
      p0.h2[1] = bf2{(__bf16)e0[2], (__bf16)e0[3]};
      p0.h2[2] = bf2{(__bf16)e1[0], (__bf16)e1[1]};
      p0.h2[3] = bf2{(__bf16)e1[2], (__bf16)e1[3]};
#pragma unroll
      for (int n = 0; n < 4; ++n)
        acc[f][n] = __builtin_amdgcn_mfma_f32_16x16x32_bf16(p0.v, vf[n], acc[f][n], 0, 0, 0);
    }
  };

  STG_FULL(0, 0);
  __syncthreads();
  int buf = 0;
  for (int t = 0; t < 14; ++t) {
    if (t < 13) STG_FULL(buf ^ 1, t + 1);
    else        STG_TAIL(buf ^ 1);
    if (active) COMP_FULL(smem[buf]);
    __syncthreads();
    buf ^= 1;
  }
  if (active) {
    COMP_TAIL(smem[buf]);
    float rinv[2];
#pragma unroll
    for (int f = 0; f < 2; ++f) {
      float e = (ellv[f][0] + ellv[f][1]) + (ellv[f][2] + ellv[f][3]);
      e += __shfl_xor(e, 16);
      e += __shfl_xor(e, 32);
      rinv[f] = 1.0f / e;
    }
#pragma unroll
    for (int f = 0; f < 2; ++f) {
      float rj[4];
#pragma unroll
      for (int j = 0; j < 4; ++j) rj[j] = __shfl(rinv[f], g * 4 + j);
      short* orow = ob + (size_t)(b * NN + q0 + f * 16 + g * 4) * CC + h * HD + c;
#pragma unroll
      for (int n = 0; n < 4; ++n)
#pragma unroll
        for (int j = 0; j < 4; ++j)
          orow[(size_t)j * CC + n * 16] = f2bf(acc[f][n][j] * rj[j]);
    }
  }
}

// ---------------------------------------------------------------------------
extern "C" void kernel_launch(void* const* d_in, const int* in_sizes, int n_in,
                              void* d_out, int out_size, void* d_ws, size_t ws_size,
                              hipStream_t stream) {
  const float* x    = (const float*)d_in[0];
  const float* xpos = (const float*)d_in[1];
  const float* k_t  = (const float*)d_in[2];
  const float* v_t  = (const float*)d_in[3];
  const float* Wq   = (const float*)d_in[4];
  const float* Wk   = (const float*)d_in[5];
  const float* Wv   = (const float*)d_in[6];
  const float* Wp   = (const float*)d_in[7];
  const float* bp   = (const float*)d_in[8];
  float* out = (float*)d_out;

  // workspace layout (bytes), total 160,432,128
  char* ws = (char*)d_ws;
  short* k_in = (short*)ws;                       // 30,408,704  [16*928,1024] bf16
  short* v_in = (short*)(ws + 30408704);          // 30,408,704
  short* wqb  = (short*)(ws + 60817408);          // 4 x 2,097,152 (Wq|Wk|Wv|Wp)
  short* wvb  = (short*)(ws + 65011712);
  short* wpb  = (short*)(ws + 67108864);
  short* qbuf = (short*)(ws + 69206016);          // 30,408,704
  short* kbuf = (short*)(ws + 99614720);          // 30,408,704
  short* vtb  = (short*)(ws + 130023424);         // 30,408,704  vt[(b*16+h)*64+d][928]
  short* attn_o = k_in;   // alias: k_in dead after fused qk GEMM

  prep_kv<<<7424, 256, 0, stream>>>(x, xpos, k_t, v_t, k_in, v_in);
  prep_w<<<2048, 256, 0, stream>>>(Wq, Wk, Wv, Wp, wqb);
  // fused q|k projection: Bw = [Wq_scaled ; Wk] (2048 rows, contiguous in ws)
  gemm256<2><<<464, 512, 0, stream>>>(k_in, wqb, qbuf, kbuf, nullptr, nullptr);
  // v projection with fused transpose into vt
  gemm256<3><<<232, 512, 0, stream>>>(v_in, wvb, vtb, nullptr, nullptr, nullptr);
  attn_fwd<<<1792, 256, 0, stream>>>(qbuf, kbuf, vtb, attn_o);
  gemm256<1><<<200, 512, 0, stream>>>(attn_o, wpb, nullptr, nullptr, out, bp);
}